// Round 8
// baseline (104.200 us; speedup 1.0000x reference)
//
#include <hip/hip_runtime.h>
#include <hip/hip_bf16.h>

#define GAMMA 0.1f
#define ETA   0.3f
#define ITERS 8   // 64-row chunks per wave: one full residency cohort
                  // (977 blocks x 4 waves = 3908 waves ~= 4096 capacity @4/SIMD)

typedef __attribute__((ext_vector_type(8))) short short8;
typedef __attribute__((ext_vector_type(4))) float f32x4;

__device__ __forceinline__ short f2bf(float x) {
    // round-to-nearest-even fp32 -> bf16 payload (R2-proven: absmax 1.56e-2)
    unsigned u = __float_as_uint(x);
    u += 0x7FFFu + ((u >> 16) & 1u);
    return (short)(u >> 16);
}

// EXACT R2 body (86 us anchor). Two register-free levers only:
//   ITERS 2->8 (setup amortization + single-cohort grid, no tail fill), and
//   __launch_bounds__(256,4) pinning VGPR<=128 — the R3/R5/R6/R7 cluster at
//   ~97us is attributed to crossing the 128-VGPR occupancy cliff (4->2
//   waves/SIMD); this bound guards the cliff. NO other changes: f2bf
//   bit-twiddle, precise div/sqrt/rsqrt, b2 in epilogue, per-mt shfl,
//   no prefetch, no LDS, no barriers.
__global__ __launch_bounds__(256, 4) void market_impact_mfma(
    const float* __restrict__ os_g, const float* __restrict__ liq_g,
    const float* __restrict__ W1,  const float* __restrict__ b1g,
    const float* __restrict__ W2,  const float* __restrict__ b2,
    const float* __restrict__ lnw, const float* __restrict__ lnb,
    float* __restrict__ out, int B)
{
    const int tid  = threadIdx.x;
    const int lane = tid & 63;
    const int g    = lane >> 4;   // k-group (0..3)
    const int c    = lane & 15;   // A row = out col (within 16-block); B col = data row

    // ---- one-time per-lane weights ----
    float u[16], v[16], bb[16];
    #pragma unroll
    for (int kc = 0; kc < 2; ++kc)
        #pragma unroll
        for (int j = 0; j < 8; ++j) {
            int k = kc * 32 + g * 8 + j;
            float w0 = W1[k], w1 = W1[64 + k], w2r = W1[128 + k];
            u[kc * 8 + j]  = w0 + w2r;
            v[kc * 8 + j]  = w1 + w2r;
            bb[kc * 8 + j] = b1g[k];
        }

    // W2^T fragments (A-operand): lane m=c is output col within block cc,
    // element j <-> k = kc*32 + g*8 + j.
    short8 wfrag[2][2];
    #pragma unroll
    for (int kc = 0; kc < 2; ++kc)
        #pragma unroll
        for (int cc = 0; cc < 2; ++cc) {
            short8 t;
            #pragma unroll
            for (int j = 0; j < 8; ++j) {
                int k = kc * 32 + g * 8 + j;
                t[j] = f2bf(W2[k * 32 + cc * 16 + c]);
            }
            wfrag[kc][cc] = t;
        }

    // epilogue constants: this lane's output cols are cc*16 + g*4 + reg
    float b2a[8], lnwa[8], lnba[8];
    #pragma unroll
    for (int cc = 0; cc < 2; ++cc) {
        float4 bq = *reinterpret_cast<const float4*>(b2  + cc * 16 + g * 4);
        float4 wq = *reinterpret_cast<const float4*>(lnw + cc * 16 + g * 4);
        float4 bl = *reinterpret_cast<const float4*>(lnb + cc * 16 + g * 4);
        b2a[cc*4+0] = bq.x; b2a[cc*4+1] = bq.y; b2a[cc*4+2] = bq.z; b2a[cc*4+3] = bq.w;
        lnwa[cc*4+0] = wq.x; lnwa[cc*4+1] = wq.y; lnwa[cc*4+2] = wq.z; lnwa[cc*4+3] = wq.w;
        lnba[cc*4+0] = bl.x; lnba[cc*4+1] = bl.y; lnba[cc*4+2] = bl.z; lnba[cc*4+3] = bl.w;
    }

    const long long wid = (long long)blockIdx.x * 4 + (tid >> 6);
    float* enc = out + 3LL * B;

    #pragma unroll 1
    for (int it = 0; it < ITERS; ++it) {
        long long base = (wid * ITERS + it) * 64;
        if (base >= B) break;                      // wave-uniform

        int r  = (int)base + lane;
        bool ok = r < B;
        float o  = ok ? os_g[r]  : 0.f;
        float lq = ok ? liq_g[r] : 1.f;
        float perm = GAMMA * o / lq;               // exact (R2)
        float temp = ETA * copysignf(sqrtf(fabsf(o)), o) * rsqrtf(lq);
        if (ok) {
            out[r]         = perm;
            out[B + r]     = temp;
            out[2 * B + r] = perm + temp;
        }

        #pragma unroll
        for (int mt = 0; mt < 4; ++mt) {
            // B-operand: h for row base + mt*16 + c, k = kc*32 + g*8 + j
            float pm = __shfl(perm, mt * 16 + c);
            float tm = __shfl(temp, mt * 16 + c);
            short8 a0, a1;
            #pragma unroll
            for (int j = 0; j < 8; ++j) {
                float h0 = fmaxf(0.f, fmaf(pm, u[j],     fmaf(tm, v[j],     bb[j])));
                float h1 = fmaxf(0.f, fmaf(pm, u[8 + j], fmaf(tm, v[8 + j], bb[8 + j])));
                a0[j] = f2bf(h0);
                a1[j] = f2bf(h1);
            }

            f32x4 d0 = {0.f, 0.f, 0.f, 0.f};
            f32x4 d1 = {0.f, 0.f, 0.f, 0.f};
            d0 = __builtin_amdgcn_mfma_f32_16x16x32_bf16(wfrag[0][0], a0, d0, 0, 0, 0);
            d0 = __builtin_amdgcn_mfma_f32_16x16x32_bf16(wfrag[1][0], a1, d0, 0, 0, 0);
            d1 = __builtin_amdgcn_mfma_f32_16x16x32_bf16(wfrag[0][1], a0, d1, 0, 0, 0);
            d1 = __builtin_amdgcn_mfma_f32_16x16x32_bf16(wfrag[1][1], a1, d1, 0, 0, 0);

            // x = d + b2 (epilogue, as R2); lane holds row (base+mt*16+c)
            float x[8];
            #pragma unroll
            for (int reg = 0; reg < 4; ++reg) {
                x[reg]     = d0[reg] + b2a[reg];
                x[4 + reg] = d1[reg] + b2a[4 + reg];
            }
            float s = 0.f, q = 0.f;
            #pragma unroll
            for (int j = 0; j < 8; ++j) { s += x[j]; q = fmaf(x[j], x[j], q); }
            s += __shfl_xor(s, 16); s += __shfl_xor(s, 32);
            q += __shfl_xor(q, 16); q += __shfl_xor(q, 32);
            float mu   = s * 0.03125f;
            float var  = fmaf(q, 0.03125f, -mu * mu);
            float rstd = rsqrtf(var + 1e-5f);

            int row = (int)base + mt * 16 + c;
            if (row < B) {
                float4 o0, o1;
                o0.x = fmaf((x[0] - mu) * rstd, lnwa[0], lnba[0]);
                o0.y = fmaf((x[1] - mu) * rstd, lnwa[1], lnba[1]);
                o0.z = fmaf((x[2] - mu) * rstd, lnwa[2], lnba[2]);
                o0.w = fmaf((x[3] - mu) * rstd, lnwa[3], lnba[3]);
                o1.x = fmaf((x[4] - mu) * rstd, lnwa[4], lnba[4]);
                o1.y = fmaf((x[5] - mu) * rstd, lnwa[5], lnba[5]);
                o1.z = fmaf((x[6] - mu) * rstd, lnwa[6], lnba[6]);
                o1.w = fmaf((x[7] - mu) * rstd, lnwa[7], lnba[7]);
                float* rp = enc + (long long)row * 32;
                *reinterpret_cast<float4*>(rp + g * 4)      = o0;
                *reinterpret_cast<float4*>(rp + 16 + g * 4) = o1;
            }
        }
    }
}

extern "C" void kernel_launch(void* const* d_in, const int* in_sizes, int n_in,
                              void* d_out, int out_size, void* d_ws, size_t ws_size,
                              hipStream_t stream) {
    const float* os_g = (const float*)d_in[0];
    const float* liq  = (const float*)d_in[1];
    const float* W1   = (const float*)d_in[2];
    const float* b1   = (const float*)d_in[3];
    const float* W2   = (const float*)d_in[4];
    const float* b2   = (const float*)d_in[5];
    const float* lnw  = (const float*)d_in[6];
    const float* lnb  = (const float*)d_in[7];
    float* out = (float*)d_out;
    const int B = in_sizes[0];

    const int rows_per_block = 4 * ITERS * 64;   // 4 waves * 8 chunks * 64 rows = 2048
    const int grid = (B + rows_per_block - 1) / rows_per_block;   // 977 for B=2M
    market_impact_mfma<<<grid, 256, 0, stream>>>(
        os_g, liq, W1, b1, W2, b2, lnw, lnb, out, B);
}

// Round 10
// 84.897 us; speedup vs baseline: 1.2274x; 1.2274x over previous
//
#include <hip/hip_runtime.h>
#include <hip/hip_bf16.h>

#define GAMMA 0.1f
#define ETA   0.3f
#define ITERS 2   // 64-row chunks per wave — EXACT R2 schedule (86 us anchor)

typedef __attribute__((ext_vector_type(8))) short short8;
typedef __attribute__((ext_vector_type(4))) float f32x4;

__device__ __forceinline__ short f2bf(float x) {
    // round-to-nearest-even fp32 -> bf16 payload (R2-proven: absmax 1.56e-2)
    unsigned u = __float_as_uint(x);
    u += 0x7FFFu + ((u >> 16) & 1u);
    return (short)(u >> 16);
}

// BYTE-IDENTICAL to the R2 kernel (86 us) except: every output store is
// __builtin_nontemporal_store (pure cache-policy bit flip on the same
// global_store instructions — zero VGPR, zero instruction-count change).
// Output is 280 MB write-once-never-read: NT skips L2 write-allocate.
// Vector stores use clang ext-vector f32x4 (HIP float4 rejected by builtin).
// This round doubles as the noise test for the R2 anchor (3-way read).
__global__ __launch_bounds__(256) void market_impact_mfma(
    const float* __restrict__ os_g, const float* __restrict__ liq_g,
    const float* __restrict__ W1,  const float* __restrict__ b1g,
    const float* __restrict__ W2,  const float* __restrict__ b2,
    const float* __restrict__ lnw, const float* __restrict__ lnb,
    float* __restrict__ out, int B)
{
    const int tid  = threadIdx.x;
    const int lane = tid & 63;
    const int g    = lane >> 4;   // k-group (0..3)
    const int c    = lane & 15;   // A row = out col (within 16-block); B col = data row

    // ---- one-time per-lane weights ----
    float u[16], v[16], bb[16];
    #pragma unroll
    for (int kc = 0; kc < 2; ++kc)
        #pragma unroll
        for (int j = 0; j < 8; ++j) {
            int k = kc * 32 + g * 8 + j;
            float w0 = W1[k], w1 = W1[64 + k], w2r = W1[128 + k];
            u[kc * 8 + j]  = w0 + w2r;
            v[kc * 8 + j]  = w1 + w2r;
            bb[kc * 8 + j] = b1g[k];
        }

    // W2^T fragments (A-operand): lane m=c is output col within block cc,
    // element j <-> k = kc*32 + g*8 + j.
    short8 wfrag[2][2];
    #pragma unroll
    for (int kc = 0; kc < 2; ++kc)
        #pragma unroll
        for (int cc = 0; cc < 2; ++cc) {
            short8 t;
            #pragma unroll
            for (int j = 0; j < 8; ++j) {
                int k = kc * 32 + g * 8 + j;
                t[j] = f2bf(W2[k * 32 + cc * 16 + c]);
            }
            wfrag[kc][cc] = t;
        }

    // epilogue constants: this lane's output cols are cc*16 + g*4 + reg
    float b2a[8], lnwa[8], lnba[8];
    #pragma unroll
    for (int cc = 0; cc < 2; ++cc) {
        float4 bq = *reinterpret_cast<const float4*>(b2  + cc * 16 + g * 4);
        float4 wq = *reinterpret_cast<const float4*>(lnw + cc * 16 + g * 4);
        float4 bl = *reinterpret_cast<const float4*>(lnb + cc * 16 + g * 4);
        b2a[cc*4+0] = bq.x; b2a[cc*4+1] = bq.y; b2a[cc*4+2] = bq.z; b2a[cc*4+3] = bq.w;
        lnwa[cc*4+0] = wq.x; lnwa[cc*4+1] = wq.y; lnwa[cc*4+2] = wq.z; lnwa[cc*4+3] = wq.w;
        lnba[cc*4+0] = bl.x; lnba[cc*4+1] = bl.y; lnba[cc*4+2] = bl.z; lnba[cc*4+3] = bl.w;
    }

    const long long wid = (long long)blockIdx.x * 4 + (tid >> 6);
    float* enc = out + 3LL * B;

    #pragma unroll 1
    for (int it = 0; it < ITERS; ++it) {
        long long base = (wid * ITERS + it) * 64;
        if (base >= B) break;                      // wave-uniform

        int r  = (int)base + lane;
        bool ok = r < B;
        float o  = ok ? os_g[r]  : 0.f;
        float lq = ok ? liq_g[r] : 1.f;
        float perm = GAMMA * o / lq;               // exact div (R2)
        float temp = ETA * copysignf(sqrtf(fabsf(o)), o) * rsqrtf(lq);
        float tot  = perm + temp;
        if (ok) {
            __builtin_nontemporal_store(perm, &out[r]);
            __builtin_nontemporal_store(temp, &out[B + r]);
            __builtin_nontemporal_store(tot,  &out[2 * B + r]);
        }

        #pragma unroll
        for (int mt = 0; mt < 4; ++mt) {
            // B-operand: h for row base + mt*16 + c, k = kc*32 + g*8 + j
            float pm = __shfl(perm, mt * 16 + c);
            float tm = __shfl(temp, mt * 16 + c);
            short8 a0, a1;
            #pragma unroll
            for (int j = 0; j < 8; ++j) {
                float h0 = fmaxf(0.f, fmaf(pm, u[j],     fmaf(tm, v[j],     bb[j])));
                float h1 = fmaxf(0.f, fmaf(pm, u[8 + j], fmaf(tm, v[8 + j], bb[8 + j])));
                a0[j] = f2bf(h0);
                a1[j] = f2bf(h1);
            }

            f32x4 d0 = {0.f, 0.f, 0.f, 0.f};
            f32x4 d1 = {0.f, 0.f, 0.f, 0.f};
            d0 = __builtin_amdgcn_mfma_f32_16x16x32_bf16(wfrag[0][0], a0, d0, 0, 0, 0);
            d0 = __builtin_amdgcn_mfma_f32_16x16x32_bf16(wfrag[1][0], a1, d0, 0, 0, 0);
            d1 = __builtin_amdgcn_mfma_f32_16x16x32_bf16(wfrag[0][1], a0, d1, 0, 0, 0);
            d1 = __builtin_amdgcn_mfma_f32_16x16x32_bf16(wfrag[1][1], a1, d1, 0, 0, 0);

            // x = d + b2 (epilogue, as R2); lane holds row (base+mt*16+c)
            float x[8];
            #pragma unroll
            for (int reg = 0; reg < 4; ++reg) {
                x[reg]     = d0[reg] + b2a[reg];
                x[4 + reg] = d1[reg] + b2a[4 + reg];
            }
            float s = 0.f, q = 0.f;
            #pragma unroll
            for (int j = 0; j < 8; ++j) { s += x[j]; q = fmaf(x[j], x[j], q); }
            s += __shfl_xor(s, 16); s += __shfl_xor(s, 32);
            q += __shfl_xor(q, 16); q += __shfl_xor(q, 32);
            float mu   = s * 0.03125f;
            float var  = fmaf(q, 0.03125f, -mu * mu);
            float rstd = rsqrtf(var + 1e-5f);

            int row = (int)base + mt * 16 + c;
            if (row < B) {
                f32x4 o0, o1;
                o0[0] = fmaf((x[0] - mu) * rstd, lnwa[0], lnba[0]);
                o0[1] = fmaf((x[1] - mu) * rstd, lnwa[1], lnba[1]);
                o0[2] = fmaf((x[2] - mu) * rstd, lnwa[2], lnba[2]);
                o0[3] = fmaf((x[3] - mu) * rstd, lnwa[3], lnba[3]);
                o1[0] = fmaf((x[4] - mu) * rstd, lnwa[4], lnba[4]);
                o1[1] = fmaf((x[5] - mu) * rstd, lnwa[5], lnba[5]);
                o1[2] = fmaf((x[6] - mu) * rstd, lnwa[6], lnba[6]);
                o1[3] = fmaf((x[7] - mu) * rstd, lnwa[7], lnba[7]);
                float* rp = enc + (long long)row * 32;
                __builtin_nontemporal_store(o0, reinterpret_cast<f32x4*>(rp + g * 4));
                __builtin_nontemporal_store(o1, reinterpret_cast<f32x4*>(rp + 16 + g * 4));
            }
        }
    }
}

extern "C" void kernel_launch(void* const* d_in, const int* in_sizes, int n_in,
                              void* d_out, int out_size, void* d_ws, size_t ws_size,
                              hipStream_t stream) {
    const float* os_g = (const float*)d_in[0];
    const float* liq  = (const float*)d_in[1];
    const float* W1   = (const float*)d_in[2];
    const float* b1   = (const float*)d_in[3];
    const float* W2   = (const float*)d_in[4];
    const float* b2   = (const float*)d_in[5];
    const float* lnw  = (const float*)d_in[6];
    const float* lnb  = (const float*)d_in[7];
    float* out = (float*)d_out;
    const int B = in_sizes[0];

    const int rows_per_block = 4 * ITERS * 64;   // 4 waves * 2 chunks * 64 rows = 512
    const int grid = (B + rows_per_block - 1) / rows_per_block;   // 3907 for B=2M
    market_impact_mfma<<<grid, 256, 0, stream>>>(
        os_g, liq, W1, b1, W2, b2, lnw, lnb, out, B);
}